// Round 1
// baseline (391.975 us; speedup 1.0000x reference)
//
#include <hip/hip_runtime.h>

#define L_SEQ 2048
#define BATCH 32
#define HID   1024
#define FLOAT_MIN -1e20f

// ---------------------------------------------------------------------------
// Kernel 1: v[b,h] = sum_g hidden[b,g] * W[g,h];  c[b] = sum_g hidden[b,g]*bias[g]
// Grid: 256 blocks -> b = bid/8, n-tile(128 cols) = bid%8. 256 threads.
// W column-tile is re-read per b but stays L2/L3 resident (W = 4 MB total).
// ---------------------------------------------------------------------------
__global__ __launch_bounds__(256) void proj_kernel(
    const float* __restrict__ hidden,   // [B,H]
    const float* __restrict__ W,        // [H,H]  (g-major, h contiguous)
    const float* __restrict__ bias,     // [H]
    float* __restrict__ v,              // [B,H]
    float* __restrict__ c)              // [B]
{
    __shared__ float  sh_hidden[HID];
    __shared__ float4 sh_part[8][32];
    __shared__ float  sh_red[4];

    const int b  = blockIdx.x >> 3;
    const int nt = blockIdx.x & 7;
    const int t  = threadIdx.x;

    // stage hidden[b,:] (4 KB) into LDS
    ((float4*)sh_hidden)[t] = ((const float4*)(hidden + (size_t)b * HID))[t];
    __syncthreads();

    const int j4   = t & 31;    // float4 column within the 128-col tile
    const int half = t >> 5;    // 0..7 : k-partition of 128 rows each
    const int n0   = nt * 128;

    float4 acc = make_float4(0.f, 0.f, 0.f, 0.f);
    const int kbase = half * 128;
    #pragma unroll 4
    for (int k = kbase; k < kbase + 128; ++k) {
        const float  hg = sh_hidden[k];                          // LDS broadcast
        const float4 w  = ((const float4*)(W + (size_t)k * HID + n0))[j4];
        acc.x += hg * w.x; acc.y += hg * w.y;
        acc.z += hg * w.z; acc.w += hg * w.w;
    }
    sh_part[half][j4] = acc;
    __syncthreads();

    if (t < 32) {
        float4 s = sh_part[0][t];
        #pragma unroll
        for (int h = 1; h < 8; ++h) {
            const float4 p = sh_part[h][t];
            s.x += p.x; s.y += p.y; s.z += p.z; s.w += p.w;
        }
        ((float4*)(v + (size_t)b * HID + n0))[t] = s;
    }

    if (nt == 0) {  // block-uniform branch: compute c[b] once per b
        float p = 0.f;
        #pragma unroll
        for (int g = t; g < HID; g += 256) p += sh_hidden[g] * bias[g];
        #pragma unroll
        for (int off = 32; off > 0; off >>= 1) p += __shfl_down(p, off, 64);
        if ((t & 63) == 0) sh_red[t >> 6] = p;
        __syncthreads();
        if (t == 0) c[b] = sh_red[0] + sh_red[1] + sh_red[2] + sh_red[3];
    }
}

// ---------------------------------------------------------------------------
// Kernel 2: energies[b,l] = v[b] . enc[l,b,:] + c[b]
// Grid: B * L/4 = 16384 blocks, 256 threads = 4 waves, one wave per l.
// enc row (l*B+b)*H is 4 KB contiguous -> float4 coalesced; v[b] staged in LDS.
// This kernel streams the full 268 MB of encoder_outputs: the HBM-bound core.
// ---------------------------------------------------------------------------
__global__ __launch_bounds__(256) void energy_kernel(
    const float* __restrict__ enc,      // [L,B,H]
    const float* __restrict__ v,        // [B,H]
    const float* __restrict__ c,        // [B]
    float* __restrict__ energies)       // [B,L]
{
    __shared__ float4 sv[256];          // v[b,:] as float4

    const int b  = blockIdx.x >> 9;     // / (L/4)
    const int lt = blockIdx.x & 511;
    const int t  = threadIdx.x;

    sv[t] = ((const float4*)(v + (size_t)b * HID))[t];
    __syncthreads();

    const int wave = t >> 6;
    const int lane = t & 63;
    const int l    = lt * 4 + wave;

    const float4* ep = (const float4*)(enc + ((size_t)l * BATCH + b) * HID);
    float acc = 0.f;
    #pragma unroll
    for (int j = 0; j < 4; ++j) {
        const float4 e  = ep[j * 64 + lane];
        const float4 vv = sv[j * 64 + lane];
        acc += e.x * vv.x + e.y * vv.y + e.z * vv.z + e.w * vv.w;
    }
    #pragma unroll
    for (int off = 32; off > 0; off >>= 1) acc += __shfl_down(acc, off, 64);
    if (lane == 0) energies[(size_t)b * L_SEQ + l] = acc + c[b];
}

// ---------------------------------------------------------------------------
// Kernel 3: masked softmax per batch row, renormalized over valid positions.
// Invalid l get energy FLOAT_MIN -> exp underflows to exact 0, so plain
// softmax over the masked energies equals the reference's masked/sums.
// Grid: B blocks, 256 threads, 8 elements/thread.
// ---------------------------------------------------------------------------
__global__ __launch_bounds__(256) void softmax_kernel(
    const float* __restrict__ energies, // [B,L]
    const int*   __restrict__ lengths,  // [B]
    float* __restrict__ out)            // [B,1,L]
{
    __shared__ float red[4];

    const int b   = blockIdx.x;
    const int t   = threadIdx.x;
    const int len = lengths[b];

    float e[8];
    float m = -INFINITY;
    #pragma unroll
    for (int i = 0; i < 8; ++i) {
        const int l = t + i * 256;
        e[i] = (l < len) ? energies[(size_t)b * L_SEQ + l] : FLOAT_MIN;
        m = fmaxf(m, e[i]);
    }
    #pragma unroll
    for (int off = 32; off > 0; off >>= 1) m = fmaxf(m, __shfl_down(m, off, 64));
    if ((t & 63) == 0) red[t >> 6] = m;
    __syncthreads();
    m = fmaxf(fmaxf(red[0], red[1]), fmaxf(red[2], red[3]));
    __syncthreads();   // before reusing red[]

    float p[8];
    float s = 0.f;
    #pragma unroll
    for (int i = 0; i < 8; ++i) {
        p[i] = __expf(e[i] - m);   // FLOAT_MIN rows underflow to exactly 0
        s += p[i];
    }
    #pragma unroll
    for (int off = 32; off > 0; off >>= 1) s += __shfl_down(s, off, 64);
    if ((t & 63) == 0) red[t >> 6] = s;
    __syncthreads();
    s = red[0] + red[1] + red[2] + red[3];

    const float inv = 1.0f / s;
    #pragma unroll
    for (int i = 0; i < 8; ++i) {
        const int l = t + i * 256;
        out[(size_t)b * L_SEQ + l] = p[i] * inv;
    }
}

// ---------------------------------------------------------------------------
extern "C" void kernel_launch(void* const* d_in, const int* in_sizes, int n_in,
                              void* d_out, int out_size, void* d_ws, size_t ws_size,
                              hipStream_t stream) {
    const float* hidden  = (const float*)d_in[0];  // (1,B,H)
    const float* enc     = (const float*)d_in[1];  // (L,B,H)
    const float* W       = (const float*)d_in[2];  // (H,H)
    const float* bias    = (const float*)d_in[3];  // (H,)
    const int*   lengths = (const int*)d_in[4];    // (B,)
    float* out = (float*)d_out;                    // (B,1,L) fp32

    // workspace layout: v[B*H] | c[B] | energies[B*L]   (~393 KB)
    float* v        = (float*)d_ws;
    float* c        = v + BATCH * HID;
    float* energies = c + BATCH;

    proj_kernel   <<<256,                   256, 0, stream>>>(hidden, W, bias, v, c);
    energy_kernel <<<BATCH * (L_SEQ / 4),   256, 0, stream>>>(enc, v, c, energies);
    softmax_kernel<<<BATCH,                 256, 0, stream>>>(energies, lengths, out);
}

// Round 2
// 384.974 us; speedup vs baseline: 1.0182x; 1.0182x over previous
//
#include <hip/hip_runtime.h>

#define L_SEQ 2048
#define BATCH 32
#define HID   1024
#define FLOAT_MIN -1e20f

// ---------------------------------------------------------------------------
// Kernel 1: v[b,h] = sum_g hidden[b,g] * W[g,h];  c[b] = sum_g hidden[b,g]*bias[g]
// Grid: 256 blocks -> b = bid/8, n-tile(128 cols) = bid%8. 256 threads.
// W column-tile is re-read per b but stays L2/L3 resident (W = 4 MB total).
// ---------------------------------------------------------------------------
__global__ __launch_bounds__(256) void proj_kernel(
    const float* __restrict__ hidden,   // [B,H]
    const float* __restrict__ W,        // [H,H]  (g-major, h contiguous)
    const float* __restrict__ bias,     // [H]
    float* __restrict__ v,              // [B,H]
    float* __restrict__ c)              // [B]
{
    __shared__ float  sh_hidden[HID];
    __shared__ float4 sh_part[8][32];
    __shared__ float  sh_red[4];

    const int b  = blockIdx.x >> 3;
    const int nt = blockIdx.x & 7;
    const int t  = threadIdx.x;

    // stage hidden[b,:] (4 KB) into LDS
    ((float4*)sh_hidden)[t] = ((const float4*)(hidden + (size_t)b * HID))[t];
    __syncthreads();

    const int j4   = t & 31;    // float4 column within the 128-col tile
    const int half = t >> 5;    // 0..7 : k-partition of 128 rows each
    const int n0   = nt * 128;

    float4 acc = make_float4(0.f, 0.f, 0.f, 0.f);
    const int kbase = half * 128;
    #pragma unroll 4
    for (int k = kbase; k < kbase + 128; ++k) {
        const float  hg = sh_hidden[k];                          // LDS broadcast
        const float4 w  = ((const float4*)(W + (size_t)k * HID + n0))[j4];
        acc.x += hg * w.x; acc.y += hg * w.y;
        acc.z += hg * w.z; acc.w += hg * w.w;
    }
    sh_part[half][j4] = acc;
    __syncthreads();

    if (t < 32) {
        float4 s = sh_part[0][t];
        #pragma unroll
        for (int h = 1; h < 8; ++h) {
            const float4 p = sh_part[h][t];
            s.x += p.x; s.y += p.y; s.z += p.z; s.w += p.w;
        }
        ((float4*)(v + (size_t)b * HID + n0))[t] = s;
    }

    if (nt == 0) {  // block-uniform branch: compute c[b] once per b
        float p = 0.f;
        #pragma unroll
        for (int g = t; g < HID; g += 256) p += sh_hidden[g] * bias[g];
        #pragma unroll
        for (int off = 32; off > 0; off >>= 1) p += __shfl_down(p, off, 64);
        if ((t & 63) == 0) sh_red[t >> 6] = p;
        __syncthreads();
        if (t == 0) c[b] = sh_red[0] + sh_red[1] + sh_red[2] + sh_red[3];
    }
}

// ---------------------------------------------------------------------------
// Kernel 2: energies[b,l] = v[b] . enc[l,b,:] + c[b]
// Flat streaming layout: one wave per enc row r = l*B + b, TWO rows per wave.
// Block of 256 (4 waves) covers 8 consecutive rows = 32 KB contiguous.
// Consecutive blocks -> consecutive memory: pure sequential stream of 268 MB.
// v (128 KB) read per-lane from global: L2-resident, no LDS, no barrier.
// ---------------------------------------------------------------------------
__global__ __launch_bounds__(256) void energy_kernel(
    const float* __restrict__ enc,      // [L,B,H] = [L*B rows][H]
    const float* __restrict__ v,        // [B,H]
    const float* __restrict__ c,        // [B]
    float* __restrict__ energies)       // [B,L]
{
    const int t    = threadIdx.x;
    const int wave = t >> 6;
    const int lane = t & 63;

    const int r0 = blockIdx.x * 8 + wave;       // first row for this wave
    const int r1 = r0 + 4;                      // second row (still in-block span)
    const int b0 = r0 & (BATCH - 1), l0 = r0 >> 5;
    const int b1 = r1 & (BATCH - 1), l1 = r1 >> 5;

    const float4* e0 = (const float4*)(enc + (size_t)r0 * HID);
    const float4* e1 = (const float4*)(enc + (size_t)r1 * HID);
    const float4* v0 = (const float4*)(v + (size_t)b0 * HID);
    const float4* v1 = (const float4*)(v + (size_t)b1 * HID);

    float a0 = 0.f, a1 = 0.f;
    #pragma unroll
    for (int j = 0; j < 4; ++j) {
        const int idx = j * 64 + lane;
        const float4 ea = e0[idx];
        const float4 eb = e1[idx];
        const float4 va = v0[idx];
        const float4 vb = v1[idx];
        a0 += ea.x * va.x + ea.y * va.y + ea.z * va.z + ea.w * va.w;
        a1 += eb.x * vb.x + eb.y * vb.y + eb.z * vb.z + eb.w * vb.w;
    }
    #pragma unroll
    for (int off = 32; off > 0; off >>= 1) {
        a0 += __shfl_down(a0, off, 64);
        a1 += __shfl_down(a1, off, 64);
    }
    if (lane == 0) {
        energies[(size_t)b0 * L_SEQ + l0] = a0 + c[b0];
        energies[(size_t)b1 * L_SEQ + l1] = a1 + c[b1];
    }
}

// ---------------------------------------------------------------------------
// Kernel 3: masked softmax per batch row, renormalized over valid positions.
// Invalid l get energy FLOAT_MIN -> exp underflows to exact 0, so plain
// softmax over the masked energies equals the reference's masked/sums.
// Grid: B blocks, 256 threads, 8 elements/thread.
// ---------------------------------------------------------------------------
__global__ __launch_bounds__(256) void softmax_kernel(
    const float* __restrict__ energies, // [B,L]
    const int*   __restrict__ lengths,  // [B]
    float* __restrict__ out)            // [B,1,L]
{
    __shared__ float red[4];

    const int b   = blockIdx.x;
    const int t   = threadIdx.x;
    const int len = lengths[b];

    float e[8];
    float m = -INFINITY;
    #pragma unroll
    for (int i = 0; i < 8; ++i) {
        const int l = t + i * 256;
        e[i] = (l < len) ? energies[(size_t)b * L_SEQ + l] : FLOAT_MIN;
        m = fmaxf(m, e[i]);
    }
    #pragma unroll
    for (int off = 32; off > 0; off >>= 1) m = fmaxf(m, __shfl_down(m, off, 64));
    if ((t & 63) == 0) red[t >> 6] = m;
    __syncthreads();
    m = fmaxf(fmaxf(red[0], red[1]), fmaxf(red[2], red[3]));
    __syncthreads();   // before reusing red[]

    float p[8];
    float s = 0.f;
    #pragma unroll
    for (int i = 0; i < 8; ++i) {
        p[i] = __expf(e[i] - m);   // FLOAT_MIN rows underflow to exactly 0
        s += p[i];
    }
    #pragma unroll
    for (int off = 32; off > 0; off >>= 1) s += __shfl_down(s, off, 64);
    if ((t & 63) == 0) red[t >> 6] = s;
    __syncthreads();
    s = red[0] + red[1] + red[2] + red[3];

    const float inv = 1.0f / s;
    #pragma unroll
    for (int i = 0; i < 8; ++i) {
        const int l = t + i * 256;
        out[(size_t)b * L_SEQ + l] = p[i] * inv;
    }
}

// ---------------------------------------------------------------------------
extern "C" void kernel_launch(void* const* d_in, const int* in_sizes, int n_in,
                              void* d_out, int out_size, void* d_ws, size_t ws_size,
                              hipStream_t stream) {
    const float* hidden  = (const float*)d_in[0];  // (1,B,H)
    const float* enc     = (const float*)d_in[1];  // (L,B,H)
    const float* W       = (const float*)d_in[2];  // (H,H)
    const float* bias    = (const float*)d_in[3];  // (H,)
    const int*   lengths = (const int*)d_in[4];    // (B,)
    float* out = (float*)d_out;                    // (B,1,L) fp32

    // workspace layout: v[B*H] | c[B] | energies[B*L]   (~393 KB)
    float* v        = (float*)d_ws;
    float* c        = v + BATCH * HID;
    float* energies = c + BATCH;

    proj_kernel   <<<256,                    256, 0, stream>>>(hidden, W, bias, v, c);
    energy_kernel <<<(L_SEQ * BATCH) / 8,    256, 0, stream>>>(enc, v, c, energies);
    softmax_kernel<<<BATCH,                  256, 0, stream>>>(energies, lengths, out);
}